// Round 4
// baseline (664.268 us; speedup 1.0000x reference)
//
#include <hip/hip_runtime.h>

typedef __bf16 bf16;
typedef __bf16 bf16x8 __attribute__((ext_vector_type(8)));
typedef float  f32x4  __attribute__((ext_vector_type(4)));

// Problem constants: B=32, N_PIC=4, C=3, H=W=224, P=16, HP=14, NP=196, D=768

// ---------------------------------------------------------------------------
// patchify + cast to bf16: x[128,3,224,224] f32 -> p[128*196, 768] bf16
__global__ __launch_bounds__(256) void patchify_k(const float* __restrict__ x,
                                                  bf16* __restrict__ p) {
  int t = blockIdx.x * 256 + threadIdx.x;
  if (t >= 128 * 3 * 14 * 16 * 14) return;
  int j  = t % 14; t /= 14;
  int ph = t % 16; t /= 16;
  int i  = t % 14; t /= 14;
  int c  = t % 3;  t /= 3;
  int bn = t;
  const float* src = x + (((long long)(bn * 3 + c) * 224 + (i * 16 + ph)) * 224 + j * 16);
  bf16* dst = p + ((long long)(bn * 196 + (i * 14 + j)) * 768 + c * 256 + ph * 16);
  bf16 tmp[16];
  for (int k = 0; k < 16; k += 4) {
    float4 f = *(const float4*)(src + k);
    tmp[k + 0] = (bf16)f.x; tmp[k + 1] = (bf16)f.y;
    tmp[k + 2] = (bf16)f.z; tmp[k + 3] = (bf16)f.w;
  }
  *(bf16x8*)(dst)     = *(bf16x8*)&tmp[0];
  *(bf16x8*)(dst + 8) = *(bf16x8*)&tmp[8];
}

// ---------------------------------------------------------------------------
// transpose + cast the 6 weights: W[k][n] f32 (768x768) -> Wt[n][k] bf16
// call order (W1, Wk, Wv, Wq, Wo1, Wo2) => wt+WSZ is the fused 1536-row KV wt.
__global__ __launch_bounds__(256) void wtrans_k(const float* __restrict__ w0,
                                                const float* __restrict__ w1,
                                                const float* __restrict__ w2,
                                                const float* __restrict__ w3,
                                                const float* __restrict__ w4,
                                                const float* __restrict__ w5,
                                                bf16* __restrict__ out) {
  __shared__ float tile[32][33];
  const float* W;
  switch (blockIdx.z) {
    case 0: W = w0; break; case 1: W = w1; break; case 2: W = w2; break;
    case 3: W = w3; break; case 4: W = w4; break; default: W = w5; break;
  }
  bf16* o = out + (long long)blockIdx.z * 768 * 768;
  int nb = blockIdx.x * 32, kb = blockIdx.y * 32;
  int c = threadIdx.x & 31, r = threadIdx.x >> 5;
  for (int rr = 0; rr < 32; rr += 8)
    tile[r + rr][c] = W[(long long)(kb + r + rr) * 768 + nb + c];
  __syncthreads();
  for (int rr = 0; rr < 32; rr += 8)
    o[(long long)(nb + r + rr) * 768 + kb + c] = (bf16)tile[c][r + rr];
}

// ---------------------------------------------------------------------------
// transpose V out of fused kv[z][196][1536] (V = cols 768..1535)
// -> Vt[z][768][224] bf16, zero-padding m in [196,224)
__global__ __launch_bounds__(256) void vtrans_k(const bf16* __restrict__ kv,
                                                bf16* __restrict__ Vt) {
  __shared__ short tile[32][33];
  int z = blockIdx.z;
  const short* v = (const short*)(kv + (long long)z * 301056 + 768);
  short* vt = (short*)(Vt + (long long)z * 768 * 224);
  int db = blockIdx.x * 32;
  int mb = blockIdx.y * 32;
  int c = threadIdx.x & 31, r = threadIdx.x >> 5;
  for (int rr = 0; rr < 32; rr += 8) {
    int m = mb + r + rr;
    short val = 0;
    if (m < 196) val = v[(long long)m * 1536 + db + c];
    tile[r + rr][c] = val;
  }
  __syncthreads();
  for (int rr = 0; rr < 32; rr += 8) {
    int d = db + r + rr;
    vt[(long long)d * 224 + mb + c] = tile[c][r + rr];
  }
}

// ---------------------------------------------------------------------------
// softmax over rows of 196 f32 scores -> bf16 attn rows padded to 224
__global__ __launch_bounds__(64) void softmax_k(const float* __restrict__ S,
                                                bf16* __restrict__ attn) {
  const int row = blockIdx.x;
  const float* sr = S + (long long)row * 196;
  const int l = threadIdx.x;
  float v0 = sr[l];
  float v1 = sr[l + 64];
  float v2 = sr[l + 128];
  float v3 = (l + 192 < 196) ? sr[l + 192] : -1e30f;
  float mx = fmaxf(fmaxf(v0, v1), fmaxf(v2, v3));
  for (int o = 32; o > 0; o >>= 1) mx = fmaxf(mx, __shfl_xor(mx, o));
  float e0 = __expf(v0 - mx);
  float e1 = __expf(v1 - mx);
  float e2 = __expf(v2 - mx);
  float e3 = (l + 192 < 196) ? __expf(v3 - mx) : 0.f;
  float s = e0 + e1 + e2 + e3;
  for (int o = 32; o > 0; o >>= 1) s += __shfl_xor(s, o);
  float inv = 1.0f / s;
  bf16* ar = attn + (long long)row * 224;
  ar[l]       = (bf16)(e0 * inv);
  ar[l + 64]  = (bf16)(e1 * inv);
  ar[l + 128] = (bf16)(e2 * inv);
  int m3 = l + 192;
  if (m3 < 196) ar[m3] = (bf16)(e3 * inv);
  else if (m3 < 224) ar[m3] = (bf16)0.0f;
}

// ---------------------------------------------------------------------------
__device__ __forceinline__ void gld16(const bf16* g, bf16* l) {
  __builtin_amdgcn_global_load_lds(
      (const __attribute__((address_space(1))) unsigned int*)g,
      (__attribute__((address_space(3))) unsigned int*)l, 16, 0, 0);
}

// s_waitcnt with lgkm=15 (no wait), exp=7 (no wait), vmcnt = N (N<16)
#define WAITVM(N) __builtin_amdgcn_s_waitcnt(0x0F70 | (N))

// Pipelined bf16 MFMA GEMM: 128x128 tile, BK=32, TRIPLE-buffered LDS,
// prefetch distance 2, raw s_barrier (no vmcnt(0) drain) + explicit
// s_waitcnt vmcnt(4) so the next tile's DMAs stay in flight across the
// barrier (AITER-style).  Per wave per tile: 4 global_load_lds dwordx4.
// WAR safety: a wave at barrier(i) has consumed tile i-1's ds_reads
// (lgkmcnt drained before its MFMAs), so slot (i+2)%3 == (i-1)%3 is free.
// C[z][i][j] = act(scale * sum_k A[i][k]*Bt[j][k] + bias'[j])
//   A row i -> (i/gr)*gs + (i%gr)*lda   (+ (z/a_zdiv)*strideAz)
//   Bt row j -> j*ldb                   (+ z*strideBz)
//   bias'[j] = (bias2 && j>=768) ? bias2[j-768] : bias[j]
// OOB tile rows/cols clamp to last valid row. Requires K % 32 == 0, K >= 64.
__global__ __launch_bounds__(256) void gemm128(
    const bf16* __restrict__ A, const bf16* __restrict__ Bt,
    const float* __restrict__ bias, const float* __restrict__ bias2,
    void* __restrict__ Cout,
    int M, int N, int K, int lda, int ldb, int gr, long long gs,
    long long strideAz, int a_zdiv, long long strideBz, long long strideCz,
    float scale, int relu, int out_bf16) {
  __shared__ __align__(16) bf16 As[3][4096];
  __shared__ __align__(16) bf16 Bs[3][4096];

  const int tid = threadIdx.x;
  const int lane = tid & 63;
  const int w = tid >> 6;
  const int wm = w & 1, wn = w >> 1;
  const int z = blockIdx.z;
  const int n0 = blockIdx.x * 128, m0 = blockIdx.y * 128;

  const bf16* Az  = A  + (long long)(z / a_zdiv) * strideAz;
  const bf16* Btz = Bt + (long long)z * strideBz;

  // staging: chunk = issue*256 + tid; row = chunk>>2, kcol = (chunk&3)*8
  const int r0 = tid >> 2, kc0 = (tid & 3) * 8;
  int ar0 = m0 + r0;       if (ar0 >= M) ar0 = M - 1;
  int ar1 = m0 + 64 + r0;  if (ar1 >= M) ar1 = M - 1;
  const bf16* aP0 = Az + (long long)(ar0 / gr) * gs + (long long)(ar0 % gr) * lda + kc0;
  const bf16* aP1 = Az + (long long)(ar1 / gr) * gs + (long long)(ar1 % gr) * lda + kc0;
  int br0 = n0 + r0;       if (br0 >= N) br0 = N - 1;
  int br1 = n0 + 64 + r0;  if (br1 >= N) br1 = N - 1;
  const bf16* bP0 = Btz + (long long)br0 * ldb + kc0;
  const bf16* bP1 = Btz + (long long)br1 * ldb + kc0;

  const int dstOff = w * 512;   // wave-uniform LDS chunk base (elements)

#define ISSUE(t, s) do { const int _o = (t) << 5;          \
    gld16(aP0 + _o, As[(s)] + dstOff);                     \
    gld16(aP1 + _o, As[(s)] + 2048 + dstOff);              \
    gld16(bP0 + _o, Bs[(s)] + dstOff);                     \
    gld16(bP1 + _o, Bs[(s)] + 2048 + dstOff); } while (0)

  const int niter = K >> 5;
  f32x4 acc[4][4] = {};
  const int fr = lane & 15, fq = lane >> 4;

  // prologue: tiles 0,1 -> slots 0,1  (8 DMAs/wave outstanding)
  ISSUE(0, 0);
  ISSUE(1, 1);

  int slot = 0;        // slot of tile i
  for (int i = 0; i < niter; ++i) {
    WAITVM(4);                        // tile i resident (tile i+1 in flight)
    __builtin_amdgcn_s_barrier();     // raw barrier: NO vmcnt(0) drain
    int pf = i + 2;  if (pf >= niter) pf = niter - 1;   // clamped dummy at tail
    int ps = slot + 2; if (ps >= 3) ps -= 3;
    ISSUE(pf, ps);                    // keeps 8 DMAs/wave outstanding

    const bf16* Ac = As[slot];
    const bf16* Bc = Bs[slot];
    bf16x8 a[4], b[4];
#pragma unroll
    for (int mi = 0; mi < 4; mi++)
      a[mi] = *(const bf16x8*)&Ac[(wm * 64 + mi * 16 + fr) * 32 + fq * 8];
#pragma unroll
    for (int ni = 0; ni < 4; ni++)
      b[ni] = *(const bf16x8*)&Bc[(wn * 64 + ni * 16 + fr) * 32 + fq * 8];
#pragma unroll
    for (int mi = 0; mi < 4; mi++)
#pragma unroll
      for (int ni = 0; ni < 4; ni++)
        acc[mi][ni] = __builtin_amdgcn_mfma_f32_16x16x32_bf16(a[mi], b[ni], acc[mi][ni], 0, 0, 0);

    slot = (slot == 2) ? 0 : slot + 1;
  }
  WAITVM(0);   // drain dummy prefetches before LDS dealloc / kernel end
#undef ISSUE

  const long long cz = (long long)z * strideCz;
#pragma unroll
  for (int ni = 0; ni < 4; ni++) {
    int col = n0 + wn * 64 + ni * 16 + fr;
    if (col >= N) continue;
    float bb = 0.f;
    if (bias) bb = (bias2 && col >= 768) ? bias2[col - 768] : bias[col];
#pragma unroll
    for (int mi = 0; mi < 4; mi++) {
      int rbase = m0 + wm * 64 + mi * 16 + fq * 4;
#pragma unroll
      for (int r = 0; r < 4; r++) {
        int row = rbase + r;
        if (row >= M) continue;
        float v = acc[mi][ni][r] * scale + bb;
        if (relu) v = fmaxf(v, 0.f);
        long long idx = cz + (long long)row * N + col;
        if (out_bf16) ((bf16*)Cout)[idx] = (bf16)v;
        else          ((float*)Cout)[idx] = v;
      }
    }
  }
}

// ---------------------------------------------------------------------------
extern "C" void kernel_launch(void* const* d_in, const int* in_sizes, int n_in,
                              void* d_out, int out_size, void* d_ws, size_t ws_size,
                              hipStream_t stream) {
  (void)in_sizes; (void)n_in; (void)out_size; (void)ws_size;
  const float* x   = (const float*)d_in[0];
  const float* W1  = (const float*)d_in[1];
  const float* b1  = (const float*)d_in[2];
  const float* Wq  = (const float*)d_in[3];
  const float* bq  = (const float*)d_in[4];
  const float* Wk  = (const float*)d_in[5];
  const float* bk  = (const float*)d_in[6];
  const float* Wv  = (const float*)d_in[7];
  const float* bv  = (const float*)d_in[8];
  const float* Wo1 = (const float*)d_in[9];
  const float* bo1 = (const float*)d_in[10];
  const float* Wo2 = (const float*)d_in[11];
  const float* bo2 = (const float*)d_in[12];

  // workspace layout (bytes), slots reused across disjoint lifetimes
  char* ws = (char*)d_ws;
  bf16*  p    = (bf16*)(ws + 0);             // [25088,768]  then vt
  bf16*  vt   = (bf16*)(ws + 0);             // [128,768,224]
  bf16*  h    = (bf16*)(ws + 44040192LL);    // [25088,768]  then wv
  bf16*  wv   = (bf16*)(ws + 44040192LL);
  bf16*  kv   = (bf16*)(ws + 82575360LL);    // [25088,1536] then o1
  bf16*  o1   = (bf16*)(ws + 82575360LL);
  float* sc   = (float*)(ws + 159645696LL);  // [128,196,196] f32
  bf16*  q    = (bf16*)(ws + 179314688LL);   // [6272,768]   then attn
  bf16*  attn = (bf16*)(ws + 179314688LL);   // [128,196,224]
  bf16*  wt   = (bf16*)(ws + 190554112LL);   // 6 x 768x768
  constexpr long long WSZ = 768LL * 768;

  const float qk_scale = 0.03608439182435161f;   // 1/sqrt(768)

  patchify_k<<<4704, 256, 0, stream>>>(x, p);
  wtrans_k<<<dim3(24, 24, 6), 256, 0, stream>>>(W1, Wk, Wv, Wq, Wo1, Wo2, wt);

  // h = p @ W1 + b1                     [25088,768] bf16
  gemm128<<<dim3(6, 196, 1), 256, 0, stream>>>(p, wt + 0 * WSZ, b1, nullptr, h,
      25088, 768, 768, 768, 768, 25088, 0LL, 0LL, 1, 0LL, 0LL, 1.f, 0, 1);
  // kv = h @ [Wk|Wv] + [bk|bv]          [25088,1536] bf16 (fused K,V)
  gemm128<<<dim3(12, 196, 1), 256, 0, stream>>>(h, wt + 1 * WSZ, bk, bv, kv,
      25088, 1536, 768, 768, 768, 25088, 0LL, 0LL, 1, 0LL, 0LL, 1.f, 0, 1);
  // q = h[:,0] @ Wq + bq                [6272,768] bf16 (remap gr=196)
  gemm128<<<dim3(6, 49, 1), 256, 0, stream>>>(h, wt + 3 * WSZ, bq, nullptr, q,
      6272, 768, 768, 768, 768, 196, 602112LL, 0LL, 1, 0LL, 0LL, 1.f, 0, 1);
  // Vt[z][d][m], m padded to 224 (from kv cols 768..1535)
  vtrans_k<<<dim3(24, 7, 128), 256, 0, stream>>>(kv, vt);
  // scores[z][s][m] = (Q[b] K[z]^T) * scale   f32 (K rows inside kv, ldb=1536)
  gemm128<<<dim3(2, 2, 128), 256, 0, stream>>>(q, kv, nullptr, nullptr, sc,
      196, 196, 768, 768, 1536, 196, 0LL, 150528LL, 4, 301056LL, 38416LL,
      qk_scale, 0, 0);
  // attn = softmax(scores), bf16, K-padded to 224
  softmax_k<<<25088, 64, 0, stream>>>(sc, attn);
  // wv[z][s][d] = attn @ Vt   (K=224)
  gemm128<<<dim3(6, 2, 128), 256, 0, stream>>>(attn, vt, nullptr, nullptr, wv,
      196, 768, 224, 224, 224, 196, 0LL, 43904LL, 1, 172032LL, 150528LL,
      1.f, 0, 1);
  // o1 = relu(wv @ Wo1 + bo1)
  gemm128<<<dim3(6, 196, 1), 256, 0, stream>>>(wv, wt + 4 * WSZ, bo1, nullptr, o1,
      25088, 768, 768, 768, 768, 25088, 0LL, 0LL, 1, 0LL, 0LL, 1.f, 1, 1);
  // out = o1 @ Wo2 + bo2   f32 -> d_out
  gemm128<<<dim3(6, 196, 1), 256, 0, stream>>>(o1, wt + 5 * WSZ, bo2, nullptr,
      (float*)d_out,
      25088, 768, 768, 768, 768, 25088, 0LL, 0LL, 1, 0LL, 0LL, 1.f, 0, 0);
}

// Round 5
// 602.668 us; speedup vs baseline: 1.1022x; 1.1022x over previous
//
#include <hip/hip_runtime.h>

typedef __bf16 bf16;
typedef __bf16 bf16x8 __attribute__((ext_vector_type(8)));
typedef float  f32x4  __attribute__((ext_vector_type(4)));

// Problem constants: B=32, N_PIC=4, C=3, H=W=224, P=16, HP=14, NP=196, D=768

// ---------------------------------------------------------------------------
// patchify + cast to bf16: x[128,3,224,224] f32 -> p[128*196, 768] bf16
__global__ __launch_bounds__(256) void patchify_k(const float* __restrict__ x,
                                                  bf16* __restrict__ p) {
  int t = blockIdx.x * 256 + threadIdx.x;
  if (t >= 128 * 3 * 14 * 16 * 14) return;
  int j  = t % 14; t /= 14;
  int ph = t % 16; t /= 16;
  int i  = t % 14; t /= 14;
  int c  = t % 3;  t /= 3;
  int bn = t;
  const float* src = x + (((long long)(bn * 3 + c) * 224 + (i * 16 + ph)) * 224 + j * 16);
  bf16* dst = p + ((long long)(bn * 196 + (i * 14 + j)) * 768 + c * 256 + ph * 16);
  bf16 tmp[16];
  for (int k = 0; k < 16; k += 4) {
    float4 f = *(const float4*)(src + k);
    tmp[k + 0] = (bf16)f.x; tmp[k + 1] = (bf16)f.y;
    tmp[k + 2] = (bf16)f.z; tmp[k + 3] = (bf16)f.w;
  }
  *(bf16x8*)(dst)     = *(bf16x8*)&tmp[0];
  *(bf16x8*)(dst + 8) = *(bf16x8*)&tmp[8];
}

// ---------------------------------------------------------------------------
// transpose + cast the 6 weights: W[k][n] f32 (768x768) -> Wt[n][k] bf16
// call order (W1, Wk, Wv, Wq, Wo1, Wo2) => wt+WSZ is the fused 1536-row KV wt.
__global__ __launch_bounds__(256) void wtrans_k(const float* __restrict__ w0,
                                                const float* __restrict__ w1,
                                                const float* __restrict__ w2,
                                                const float* __restrict__ w3,
                                                const float* __restrict__ w4,
                                                const float* __restrict__ w5,
                                                bf16* __restrict__ out) {
  __shared__ float tile[32][33];
  const float* W;
  switch (blockIdx.z) {
    case 0: W = w0; break; case 1: W = w1; break; case 2: W = w2; break;
    case 3: W = w3; break; case 4: W = w4; break; default: W = w5; break;
  }
  bf16* o = out + (long long)blockIdx.z * 768 * 768;
  int nb = blockIdx.x * 32, kb = blockIdx.y * 32;
  int c = threadIdx.x & 31, r = threadIdx.x >> 5;
  for (int rr = 0; rr < 32; rr += 8)
    tile[r + rr][c] = W[(long long)(kb + r + rr) * 768 + nb + c];
  __syncthreads();
  for (int rr = 0; rr < 32; rr += 8)
    o[(long long)(nb + r + rr) * 768 + kb + c] = (bf16)tile[c][r + rr];
}

// ---------------------------------------------------------------------------
// transpose V out of fused kv[z][196][1536] (V = cols 768..1535)
// -> Vt[z][768][224] bf16, zero-padding m in [196,224)
__global__ __launch_bounds__(256) void vtrans_k(const bf16* __restrict__ kv,
                                                bf16* __restrict__ Vt) {
  __shared__ short tile[32][33];
  int z = blockIdx.z;
  const short* v = (const short*)(kv + (long long)z * 301056 + 768);
  short* vt = (short*)(Vt + (long long)z * 768 * 224);
  int db = blockIdx.x * 32;
  int mb = blockIdx.y * 32;
  int c = threadIdx.x & 31, r = threadIdx.x >> 5;
  for (int rr = 0; rr < 32; rr += 8) {
    int m = mb + r + rr;
    short val = 0;
    if (m < 196) val = v[(long long)m * 1536 + db + c];
    tile[r + rr][c] = val;
  }
  __syncthreads();
  for (int rr = 0; rr < 32; rr += 8) {
    int d = db + r + rr;
    vt[(long long)d * 224 + mb + c] = tile[c][r + rr];
  }
}

// ---------------------------------------------------------------------------
// softmax over rows of 196 f32 scores -> bf16 attn rows padded to 224
__global__ __launch_bounds__(64) void softmax_k(const float* __restrict__ S,
                                                bf16* __restrict__ attn) {
  const int row = blockIdx.x;
  const float* sr = S + (long long)row * 196;
  const int l = threadIdx.x;
  float v0 = sr[l];
  float v1 = sr[l + 64];
  float v2 = sr[l + 128];
  float v3 = (l + 192 < 196) ? sr[l + 192] : -1e30f;
  float mx = fmaxf(fmaxf(v0, v1), fmaxf(v2, v3));
  for (int o = 32; o > 0; o >>= 1) mx = fmaxf(mx, __shfl_xor(mx, o));
  float e0 = __expf(v0 - mx);
  float e1 = __expf(v1 - mx);
  float e2 = __expf(v2 - mx);
  float e3 = (l + 192 < 196) ? __expf(v3 - mx) : 0.f;
  float s = e0 + e1 + e2 + e3;
  for (int o = 32; o > 0; o >>= 1) s += __shfl_xor(s, o);
  float inv = 1.0f / s;
  bf16* ar = attn + (long long)row * 224;
  ar[l]       = (bf16)(e0 * inv);
  ar[l + 64]  = (bf16)(e1 * inv);
  ar[l + 128] = (bf16)(e2 * inv);
  int m3 = l + 192;
  if (m3 < 196) ar[m3] = (bf16)(e3 * inv);
  else if (m3 < 224) ar[m3] = (bf16)0.0f;
}

// ---------------------------------------------------------------------------
__device__ __forceinline__ void gld16(const bf16* g, bf16* l) {
  __builtin_amdgcn_global_load_lds(
      (const __attribute__((address_space(1))) unsigned int*)g,
      (__attribute__((address_space(3))) unsigned int*)l, 16, 0, 0);
}

// Pipelined bf16 MFMA GEMM: 128x128 tile, BK=32, double-buffered LDS.
// LDS layout is kc-major per 16-row group (physical chunk = kc*16 + row%16):
// fragment ds_read_b128 banks become 4*(fr%8) -> uniform 2-way (conflict-free,
// m136), vs 8-way for the naive row-major [128][32]. The global_load_lds
// lane->global mapping is permuted to match (coalescing is address-set based,
// unchanged). Epilogue stages C through LDS for fully coalesced 256B-row
// global writes (kills partial-line RMW write amplification).
// C[z][i][j] = act(scale * sum_k A[i][k]*Bt[j][k] + bias'[j])
//   A row i -> (i/gr)*gs + (i%gr)*lda   (+ (z/a_zdiv)*strideAz)
//   Bt row j -> j*ldb                   (+ z*strideBz)
//   bias'[j] = (bias2 && j>=768) ? bias2[j-768] : bias[j]
// OOB tile rows clamp to last valid row. Requires K % 32 == 0.
// bf16 output requires N % 128 == 0 (true for all bf16 calls here).
__global__ __launch_bounds__(256) void gemm128(
    const bf16* __restrict__ A, const bf16* __restrict__ Bt,
    const float* __restrict__ bias, const float* __restrict__ bias2,
    void* __restrict__ Cout,
    int M, int N, int K, int lda, int ldb, int gr, long long gs,
    long long strideAz, int a_zdiv, long long strideBz, long long strideCz,
    float scale, int relu, int out_bf16) {
  // union: K-loop double buffers (32 KB) / epilogue C staging (<= 34816 B)
  __shared__ __align__(16) char smem[34816];
  bf16* AsBuf = (bf16*)smem;              // [2][4096]
  bf16* BsBuf = (bf16*)(smem + 16384);    // [2][4096]

  const int tid = threadIdx.x;
  const int lane = tid & 63;
  const int w = tid >> 6;
  const int wm = w & 1, wn = w >> 1;
  const int z = blockIdx.z;
  const int n0 = blockIdx.x * 128, m0 = blockIdx.y * 128;

  const bf16* Az  = A  + (long long)(z / a_zdiv) * strideAz;
  const bf16* Btz = Bt + (long long)z * strideBz;

  // staging mapping (kc-major): wave w, lane l covers logical
  // (row = 16*w + (l&15), kc = l>>4) of each 64-row half-tile.
  const int rl  = 16 * w + (lane & 15);       // 0..63
  const int kc8 = (lane >> 4) * 8;            // 0,8,16,24
  int ar0 = m0 + rl;        if (ar0 >= M) ar0 = M - 1;
  int ar1 = m0 + 64 + rl;   if (ar1 >= M) ar1 = M - 1;
  const bf16* aP0 = Az + (long long)(ar0 / gr) * gs + (long long)(ar0 % gr) * lda + kc8;
  const bf16* aP1 = Az + (long long)(ar1 / gr) * gs + (long long)(ar1 % gr) * lda + kc8;
  int br0 = n0 + rl;        if (br0 >= N) br0 = N - 1;
  int br1 = n0 + 64 + rl;   if (br1 >= N) br1 = N - 1;
  const bf16* bP0 = Btz + (long long)br0 * ldb + kc8;
  const bf16* bP1 = Btz + (long long)br1 * ldb + kc8;

  const int dstOff = w * 512;   // wave-uniform LDS chunk window (elements)

#define ISSUE(t, buf) do { const int _o = (t) << 5;                 \
    gld16(aP0 + _o, AsBuf + (buf) * 4096 + dstOff);                 \
    gld16(aP1 + _o, AsBuf + (buf) * 4096 + 2048 + dstOff);          \
    gld16(bP0 + _o, BsBuf + (buf) * 4096 + dstOff);                 \
    gld16(bP1 + _o, BsBuf + (buf) * 4096 + 2048 + dstOff); } while (0)

  const int niter = K >> 5;
  f32x4 acc[4][4] = {};
  const int fr = lane & 15, fq = lane >> 4;

  ISSUE(0, 0);   // prologue: tile 0 -> buf 0

  for (int i = 0; i < niter; ++i) {
    __syncthreads();   // drains vmcnt(0): tile i resident; prev reads done
    const int cur = i & 1;
    if (i + 1 < niter) ISSUE(i + 1, cur ^ 1);

    const bf16* Ac = AsBuf + cur * 4096;
    const bf16* Bc = BsBuf + cur * 4096;
    bf16x8 a[4], b[4];
    // frag (half, sub) lives at elements (half*4+sub)*512 + fq*128 + fr*8
#pragma unroll
    for (int mi = 0; mi < 4; mi++)
      a[mi] = *(const bf16x8*)&Ac[(wm * 4 + mi) * 512 + fq * 128 + fr * 8];
#pragma unroll
    for (int ni = 0; ni < 4; ni++)
      b[ni] = *(const bf16x8*)&Bc[(wn * 4 + ni) * 512 + fq * 128 + fr * 8];
#pragma unroll
    for (int mi = 0; mi < 4; mi++)
#pragma unroll
      for (int ni = 0; ni < 4; ni++)
        acc[mi][ni] = __builtin_amdgcn_mfma_f32_16x16x32_bf16(a[mi], b[ni], acc[mi][ni], 0, 0, 0);
  }
#undef ISSUE

  __syncthreads();   // all waves finished reading As/Bs; smem is reusable

  const long long cz = (long long)z * strideCz;
  if (out_bf16) {
    // stage full 128x128 bf16 tile, padded rows (136 elems = 272B: +2-bank
    // shift per row), then write 256B-contiguous row segments.
    bf16* Cs = (bf16*)smem;   // [128][136]
#pragma unroll
    for (int ni = 0; ni < 4; ni++) {
      int col = wn * 64 + ni * 16 + fr;
      int gcol = n0 + col;
      float bb = 0.f;
      if (bias) bb = (bias2 && gcol >= 768) ? bias2[gcol - 768] : bias[gcol];
#pragma unroll
      for (int mi = 0; mi < 4; mi++) {
        int rbase = wm * 64 + mi * 16 + fq * 4;
#pragma unroll
        for (int r = 0; r < 4; r++) {
          float v = acc[mi][ni][r] * scale + bb;
          if (relu) v = fmaxf(v, 0.f);
          Cs[(rbase + r) * 136 + col] = (bf16)v;
        }
      }
    }
    __syncthreads();
    bf16* Cp = (bf16*)Cout;
    const int rr = tid >> 4, cc = (tid & 15) * 8;
#pragma unroll
    for (int pp = 0; pp < 8; pp++) {
      int row = pp * 16 + rr;
      int grow = m0 + row;
      if (grow < M)
        *(bf16x8*)(Cp + cz + (long long)grow * N + n0 + cc) =
            *(const bf16x8*)&Cs[row * 136 + cc];
    }
  } else {
    // f32: two half-tiles of 64x128 staged at [64][132]
    float* Cs = (float*)smem;
    float* Cp = (float*)Cout;
    for (int half = 0; half < 2; ++half) {
      if (wm == half) {
#pragma unroll
        for (int ni = 0; ni < 4; ni++) {
          int col = wn * 64 + ni * 16 + fr;
          int gcol = n0 + col;
          float bb = 0.f;
          if (bias && gcol < N)
            bb = (bias2 && gcol >= 768) ? bias2[gcol - 768] : bias[gcol];
#pragma unroll
          for (int mi = 0; mi < 4; mi++) {
            int rbase = mi * 16 + fq * 4;
#pragma unroll
            for (int r = 0; r < 4; r++) {
              float v = acc[mi][ni][r] * scale + bb;
              if (relu) v = fmaxf(v, 0.f);
              Cs[(rbase + r) * 132 + col] = v;
            }
          }
        }
      }
      __syncthreads();
      const int rr = tid >> 5, cc = (tid & 31) * 4;
#pragma unroll
      for (int pp = 0; pp < 8; pp++) {
        int row = pp * 8 + rr;
        int grow = m0 + half * 64 + row;
        if (grow < M) {
          int gcol = n0 + cc;
          float* dst = Cp + cz + (long long)grow * N + gcol;
          const float* srcl = &Cs[row * 132 + cc];
          if (gcol + 4 <= N) {
            *(float4*)dst = *(const float4*)srcl;
          } else {
            for (int e = 0; e < 4; e++)
              if (gcol + e < N) dst[e] = srcl[e];
          }
        }
      }
      __syncthreads();
    }
  }
}

// ---------------------------------------------------------------------------
extern "C" void kernel_launch(void* const* d_in, const int* in_sizes, int n_in,
                              void* d_out, int out_size, void* d_ws, size_t ws_size,
                              hipStream_t stream) {
  (void)in_sizes; (void)n_in; (void)out_size; (void)ws_size;
  const float* x   = (const float*)d_in[0];
  const float* W1  = (const float*)d_in[1];
  const float* b1  = (const float*)d_in[2];
  const float* Wq  = (const float*)d_in[3];
  const float* bq  = (const float*)d_in[4];
  const float* Wk  = (const float*)d_in[5];
  const float* bk  = (const float*)d_in[6];
  const float* Wv  = (const float*)d_in[7];
  const float* bv  = (const float*)d_in[8];
  const float* Wo1 = (const float*)d_in[9];
  const float* bo1 = (const float*)d_in[10];
  const float* Wo2 = (const float*)d_in[11];
  const float* bo2 = (const float*)d_in[12];

  // workspace layout (bytes), slots reused across disjoint lifetimes
  char* ws = (char*)d_ws;
  bf16*  p    = (bf16*)(ws + 0);             // [25088,768]  then vt
  bf16*  vt   = (bf16*)(ws + 0);             // [128,768,224]
  bf16*  h    = (bf16*)(ws + 44040192LL);    // [25088,768]  then wv
  bf16*  wv   = (bf16*)(ws + 44040192LL);
  bf16*  kv   = (bf16*)(ws + 82575360LL);    // [25088,1536] then o1
  bf16*  o1   = (bf16*)(ws + 82575360LL);
  float* sc   = (float*)(ws + 159645696LL);  // [128,196,196] f32
  bf16*  q    = (bf16*)(ws + 179314688LL);   // [6272,768]   then attn
  bf16*  attn = (bf16*)(ws + 179314688LL);   // [128,196,224]
  bf16*  wt   = (bf16*)(ws + 190554112LL);   // 6 x 768x768
  constexpr long long WSZ = 768LL * 768;

  const float qk_scale = 0.03608439182435161f;   // 1/sqrt(768)

  patchify_k<<<4704, 256, 0, stream>>>(x, p);
  wtrans_k<<<dim3(24, 24, 6), 256, 0, stream>>>(W1, Wk, Wv, Wq, Wo1, Wo2, wt);

  // h = p @ W1 + b1                     [25088,768] bf16
  gemm128<<<dim3(6, 196, 1), 256, 0, stream>>>(p, wt + 0 * WSZ, b1, nullptr, h,
      25088, 768, 768, 768, 768, 25088, 0LL, 0LL, 1, 0LL, 0LL, 1.f, 0, 1);
  // kv = h @ [Wk|Wv] + [bk|bv]          [25088,1536] bf16 (fused K,V)
  gemm128<<<dim3(12, 196, 1), 256, 0, stream>>>(h, wt + 1 * WSZ, bk, bv, kv,
      25088, 1536, 768, 768, 768, 25088, 0LL, 0LL, 1, 0LL, 0LL, 1.f, 0, 1);
  // q = h[:,0] @ Wq + bq                [6272,768] bf16 (remap gr=196)
  gemm128<<<dim3(6, 49, 1), 256, 0, stream>>>(h, wt + 3 * WSZ, bq, nullptr, q,
      6272, 768, 768, 768, 768, 196, 602112LL, 0LL, 1, 0LL, 0LL, 1.f, 0, 1);
  // Vt[z][d][m], m padded to 224 (from kv cols 768..1535)
  vtrans_k<<<dim3(24, 7, 128), 256, 0, stream>>>(kv, vt);
  // scores[z][s][m] = (Q[b] K[z]^T) * scale   f32 (K rows inside kv, ldb=1536)
  gemm128<<<dim3(2, 2, 128), 256, 0, stream>>>(q, kv, nullptr, nullptr, sc,
      196, 196, 768, 768, 1536, 196, 0LL, 150528LL, 4, 301056LL, 38416LL,
      qk_scale, 0, 0);
  // attn = softmax(scores), bf16, K-padded to 224
  softmax_k<<<25088, 64, 0, stream>>>(sc, attn);
  // wv[z][s][d] = attn @ Vt   (K=224)
  gemm128<<<dim3(6, 2, 128), 256, 0, stream>>>(attn, vt, nullptr, nullptr, wv,
      196, 768, 224, 224, 224, 196, 0LL, 43904LL, 1, 172032LL, 150528LL,
      1.f, 0, 1);
  // o1 = relu(wv @ Wo1 + bo1)
  gemm128<<<dim3(6, 196, 1), 256, 0, stream>>>(wv, wt + 4 * WSZ, bo1, nullptr, o1,
      25088, 768, 768, 768, 768, 25088, 0LL, 0LL, 1, 0LL, 0LL, 1.f, 1, 1);
  // out = o1 @ Wo2 + bo2   f32 -> d_out
  gemm128<<<dim3(6, 196, 1), 256, 0, stream>>>(o1, wt + 5 * WSZ, bo2, nullptr,
      (float*)d_out,
      25088, 768, 768, 768, 768, 25088, 0LL, 0LL, 1, 0LL, 0LL, 1.f, 0, 0);
}